// Round 8
// baseline (175.342 us; speedup 1.0000x reference)
//
#include <hip/hip_runtime.h>

// BoxConv2d, two-kernel version.
// K1: per (b,c) build padded integral image I (129 x 132 fp32) in LDS, dump to d_ws.
//     Total 256 x 68112 B = 17.4 MB (fits aggregate L2; ~2 MB working set per XCD).
// K2: per (b,c, half-of-F) x 8 waves = (fi, h-half). Stage A reads I rows from
//     GLOBAL (VMEM pipe, L2-hot) instead of LDS -> DS pipe only carries Drow
//     write + Stage-B gathers. LDS = 10.5 KB -> occupancy VGPR-bound.
//     Stage-A prefetch rides vmcnt, independent of Stage-B lgkmcnt waits.

constexpr int H = 128, W = 128, C = 32, F = 8;
constexpr int STRIDE = 132;             // I row stride (floats); rows 16B-aligned
constexpr int NROW = 129;
constexpr int ISZ = NROW * STRIDE;      // 17028 floats per (b,c)

__global__ __launch_bounds__(256)
void build_integral(const float* __restrict__ in, float* __restrict__ Ig)
{
    __shared__ float I[ISZ];
    const int tid = threadIdx.x;
    const int bc  = blockIdx.x;

    // zero row 0 (cols 0..131) and col 0 (rows 0..128)
    if (tid < STRIDE) I[tid] = 0.f;
    if (tid < NROW)   I[tid * STRIDE] = 0.f;
    __syncthreads();

    // row scans: thread r scans input row r, writes I[r+1][1..128]
    const float* img = in + (size_t)bc * (H * W);
    if (tid < H) {
        const float4* row4 = (const float4*)(img + tid * W);
        float* Irow = I + (tid + 1) * STRIDE + 1;
        float acc = 0.f;
        #pragma unroll 8
        for (int w4 = 0; w4 < W / 4; ++w4) {
            float4 v = row4[w4];
            float s0 = acc + v.x, s1 = s0 + v.y, s2 = s1 + v.z, s3 = s2 + v.w;
            Irow[w4 * 4 + 0] = s0;
            Irow[w4 * 4 + 1] = s1;
            Irow[w4 * 4 + 2] = s2;
            Irow[w4 * 4 + 3] = s3;
            acc = s3;
        }
    }
    __syncthreads();

    // col scans: thread t scans column t+1 over rows 1..128, reg-chunked
    if (tid < W) {
        const int cc = tid + 1;
        float acc = 0.f;
        for (int chunk = 0; chunk < 4; ++chunk) {
            const int r0 = 1 + chunk * 32;
            float v[32];
            #pragma unroll
            for (int i = 0; i < 32; ++i) v[i] = I[(r0 + i) * STRIDE + cc];
            #pragma unroll
            for (int i = 0; i < 32; ++i) { acc += v[i]; v[i] = acc; }
            #pragma unroll
            for (int i = 0; i < 32; ++i) I[(r0 + i) * STRIDE + cc] = v[i];
        }
    }
    __syncthreads();

    // dump to global (16B-aligned: 68112 % 16 == 0)
    const float4* src = (const float4*)I;
    float4* dst = (float4*)(Ig + (size_t)bc * ISZ);
    for (int i = tid; i < ISZ / 4; i += 256) dst[i] = src[i];
}

__global__ __launch_bounds__(512, 4)
void boxconv_kernel(const float* __restrict__ Ig,
                    const float* __restrict__ x_min,
                    const float* __restrict__ x_max,
                    const float* __restrict__ y_min,
                    const float* __restrict__ y_max,
                    float* __restrict__ out)
{
    __shared__ float Dbuf[8][2 * STRIDE];   // 8448 B
    __shared__ float Dtail[8][64];          // 2048 B (total 10.5 KB)

    const int tid  = threadIdx.x;
    const int lane = tid & 63;
    const int wid  = tid >> 6;

    const int bc     = blockIdx.x >> 1;   // b*32 + c
    const int half_f = blockIdx.x & 1;    // filters 0-3 or 4-7
    const int c      = bc & 31;

    const float* Ibc = Ig + (size_t)bc * ISZ;

    const int fi    = wid >> 1;
    const int f     = half_f * 4 + fi;
    const int hbase = (wid & 1) * 64;

    const float xm = x_min[c * F + f] * 128.f;
    const float xM = x_max[c * F + f] * 128.f;
    const float ym = y_min[c * F + f] * 128.f;
    const float yM = y_max[c * F + f] * 128.f;

    // column coefficients for cols lane, lane+64 (constant over h)
    int   j0[2], j1[2];
    float b1v[2], cb1[2], nb0v[2], ncb0[2];
    #pragma unroll
    for (int k = 0; k < 2; ++k) {
        const float wf = (float)(lane + 64 * k);
        const float v0 = fminf(fmaxf(wf + ym, 0.f), 128.f);
        const float v1 = fminf(fmaxf(wf + yM + 1.f, 0.f), 128.f);
        const float j0f = fminf(floorf(v0), 127.f);
        const float j1f = fminf(floorf(v1), 127.f);
        j0[k] = (int)j0f;  j1[k] = (int)j1f;
        const float b0 = v0 - j0f, b1 = v1 - j1f;
        b1v[k] = b1; cb1[k] = 1.f - b1;
        nb0v[k] = -b0; ncb0[k] = -(1.f - b0);
    }

    const int rsub = lane >> 5;         // 0: row h, 1: row h+1
    const int wp   = (lane & 31) * 4;   // columns wp..wp+3
    float* Dw = Dbuf[wid];
    float* Dt = Dtail[wid];

    // row-interp coefficients + global row pointers for row (h + rsub)
    auto rowCoef = [&](int h, const float*& p0, const float*& p1,
                       float& a0, float& a1, float& ca0, float& ca1) {
        const float hf = (float)(h + rsub);
        const float u0 = fminf(fmaxf(hf + xm, 0.f), 128.f);
        const float u1 = fminf(fmaxf(hf + xM + 1.f, 0.f), 128.f);
        const float i0f = fminf(floorf(u0), 127.f);
        const float i1f = fminf(floorf(u1), 127.f);
        a0 = u0 - i0f; a1 = u1 - i1f; ca0 = 1.f - a0; ca1 = 1.f - a1;
        p0 = Ibc + (int)i0f * STRIDE;
        p1 = Ibc + (int)i1f * STRIDE;
    };

    // precompute col-128 Drow tails: lane r handles row hbase+r (global reads, once)
    {
        const float hf = (float)(hbase + lane);
        const float u0 = fminf(fmaxf(hf + xm, 0.f), 128.f);
        const float u1 = fminf(fmaxf(hf + xM + 1.f, 0.f), 128.f);
        const float i0f = fminf(floorf(u0), 127.f);
        const float i1f = fminf(floorf(u1), 127.f);
        const int i0 = (int)i0f, i1 = (int)i1f;
        const float a0 = u0 - i0f, a1 = u1 - i1f;
        const float t = (1.f - a1) * Ibc[i1 * STRIDE + 128] + a1 * Ibc[(i1 + 1) * STRIDE + 128]
                      - (1.f - a0) * Ibc[i0 * STRIDE + 128] - a0 * Ibc[(i0 + 1) * STRIDE + 128];
        Dt[(lane & 1) * 32 + (lane >> 1)] = t;   // index [rsub*32 + it]
    }

    float* outf = out + ((size_t)bc * F + f) * (size_t)(H * W);

    // software-pipelined main loop: Stage-A global loads (vmcnt) prefetched one
    // iteration ahead; Stage-B LDS waits (lgkmcnt) don't drain them.
    const float *p0, *p1;
    float a0, a1, ca0, ca1;
    rowCoef(hbase, p0, p1, a0, a1, ca0, ca1);
    float4 q0  = *(const float4*)(p0 + wp);
    float4 q0b = *(const float4*)(p0 + STRIDE + wp);
    float4 q1  = *(const float4*)(p1 + wp);
    float4 q1b = *(const float4*)(p1 + STRIDE + wp);

    for (int it = 0; it < 32; ++it) {
        const int h = hbase + it * 2;

        // Stage A: row-interpolated difference -> Dw (one ds_write_b128)
        float4 d;
        d.x = ca1 * q1.x + a1 * q1b.x - ca0 * q0.x - a0 * q0b.x;
        d.y = ca1 * q1.y + a1 * q1b.y - ca0 * q0.y - a0 * q0b.y;
        d.z = ca1 * q1.z + a1 * q1b.z - ca0 * q0.z - a0 * q0b.z;
        d.w = ca1 * q1.w + a1 * q1b.w - ca0 * q0.w - a0 * q0b.w;
        *(float4*)(Dw + rsub * STRIDE + wp) = d;
        if ((lane & 31) == 31) Dw[rsub * STRIDE + 128] = Dt[rsub * 32 + it];

        // Stage B gathers (in-order DS pipe sees the writes above)
        float Dj0[2][2], Dj0p[2][2], Dj1[2][2], Dj1p[2][2];
        #pragma unroll
        for (int rr = 0; rr < 2; ++rr) {
            const float* Dr = Dw + rr * STRIDE;
            #pragma unroll
            for (int k = 0; k < 2; ++k) {
                const float* pj0 = Dr + j0[k];
                const float* pj1 = Dr + j1[k];
                Dj0[rr][k] = pj0[0]; Dj0p[rr][k] = pj0[1];
                Dj1[rr][k] = pj1[0]; Dj1p[rr][k] = pj1[1];
            }
        }

        // prefetch next iteration's Stage-A rows from global (independent, vmcnt)
        rowCoef(h + 2, p0, p1, a0, a1, ca0, ca1);
        q0  = *(const float4*)(p0 + wp);
        q0b = *(const float4*)(p0 + STRIDE + wp);
        q1  = *(const float4*)(p1 + wp);
        q1b = *(const float4*)(p1 + STRIDE + wp);

        // Stage B compute + store
        #pragma unroll
        for (int rr = 0; rr < 2; ++rr) {
            float* orow = outf + (size_t)(h + rr) * W;
            #pragma unroll
            for (int k = 0; k < 2; ++k) {
                const float o = cb1[k] * Dj1[rr][k] + b1v[k] * Dj1p[rr][k]
                              + ncb0[k] * Dj0[rr][k] + nb0v[k] * Dj0p[rr][k];
                orow[lane + 64 * k] = o;
            }
        }
    }
}

extern "C" void kernel_launch(void* const* d_in, const int* in_sizes, int n_in,
                              void* d_out, int out_size, void* d_ws, size_t ws_size,
                              hipStream_t stream) {
    const float* in    = (const float*)d_in[0];
    const float* x_min = (const float*)d_in[1];
    const float* x_max = (const float*)d_in[2];
    const float* y_min = (const float*)d_in[3];
    const float* y_max = (const float*)d_in[4];
    float* outp = (float*)d_out;
    float* Ig   = (float*)d_ws;     // needs 256*17028*4 = 17.4 MB

    build_integral<<<dim3(8 * 32), dim3(256), 0, stream>>>(in, Ig);
    boxconv_kernel<<<dim3(8 * 32 * 2), dim3(512), 0, stream>>>(
        Ig, x_min, x_max, y_min, y_max, outp);
}

// Round 9
// 158.954 us; speedup vs baseline: 1.1031x; 1.1031x over previous
//
#include <hip/hip_runtime.h>

// BoxConv2d via LDS integral image (R7 structure + float2-store col remap).
// Grid 512 = (b,c) x (half of F). Block 512 threads = 8 waves.
// Wave = (filter fi = wid>>1, h-half = wid&1); per iteration 2 output rows:
// lanes 0-31 -> row h, lanes 32-63 -> row h+1 (Stage A).
// Stage B: lane covers ADJACENT cols {2*lane, 2*lane+1} -> one float2 store.
// LDS 78.6 KB -> 2 blocks/CU. SW-pipelined Stage-A prefetch; col-128 tails
// precomputed per wave.

constexpr int H = 128, W = 128, C = 32, F = 8;
constexpr int STRIDE = 132;   // I row stride (floats); 16B-aligned rows
constexpr int NROW = 129;

__global__ __launch_bounds__(512, 4)
void boxconv_kernel(const float* __restrict__ in,
                    const float* __restrict__ x_min,
                    const float* __restrict__ x_max,
                    const float* __restrict__ y_min,
                    const float* __restrict__ y_max,
                    float* __restrict__ out)
{
    __shared__ float I[NROW * STRIDE];      // 68112 B
    __shared__ float Dbuf[8][2 * STRIDE];   //  8448 B
    __shared__ float Dtail[8][64];          //  2048 B  (total 78608 B)

    const int tid  = threadIdx.x;
    const int lane = tid & 63;
    const int wid  = tid >> 6;

    const int bc     = blockIdx.x >> 1;   // b*32 + c
    const int half_f = blockIdx.x & 1;    // filters 0-3 or 4-7
    const int c      = bc & 31;

    // ---- zero row 0 and col 0 of I (rest overwritten) ----
    if (tid < NROW) I[tid * STRIDE] = 0.f;
    else if (tid < NROW + STRIDE - 1) I[tid - 128] = 0.f;   // row0 cols 1..131
    __syncthreads();

    // ---- row scans: thread r scans input row r, writes I[r+1][1..128] ----
    const float* img = in + (size_t)bc * (H * W);
    if (tid < H) {
        const float4* row4 = (const float4*)(img + tid * W);
        float* Irow = I + (tid + 1) * STRIDE + 1;
        float acc = 0.f;
        #pragma unroll 8
        for (int w4 = 0; w4 < W / 4; ++w4) {
            float4 v = row4[w4];
            float s0 = acc + v.x, s1 = s0 + v.y, s2 = s1 + v.z, s3 = s2 + v.w;
            Irow[w4 * 4 + 0] = s0;
            Irow[w4 * 4 + 1] = s1;
            Irow[w4 * 4 + 2] = s2;
            Irow[w4 * 4 + 3] = s3;
            acc = s3;
        }
    }
    __syncthreads();

    // ---- col scans: thread t scans column t+1 over rows 1..128, reg-chunked ----
    if (tid < W) {
        const int cc = tid + 1;
        float acc = 0.f;
        for (int chunk = 0; chunk < 4; ++chunk) {
            const int r0 = 1 + chunk * 32;
            float v[32];
            #pragma unroll
            for (int i = 0; i < 32; ++i) v[i] = I[(r0 + i) * STRIDE + cc];
            #pragma unroll
            for (int i = 0; i < 32; ++i) { acc += v[i]; v[i] = acc; }
            #pragma unroll
            for (int i = 0; i < 32; ++i) I[(r0 + i) * STRIDE + cc] = v[i];
        }
    }
    __syncthreads();

    // ---- main loop setup: wave = (fi, h-half) ----
    const int fi    = wid >> 1;
    const int f     = half_f * 4 + fi;
    const int hbase = (wid & 1) * 64;

    const float xm = x_min[c * F + f] * 128.f;
    const float xM = x_max[c * F + f] * 128.f;
    const float ym = y_min[c * F + f] * 128.f;
    const float yM = y_max[c * F + f] * 128.f;

    // column coefficients for ADJACENT cols 2*lane+k, k=0,1 (constant over h)
    int   j0[2], j1[2];
    float b1v[2], cb1[2], nb0v[2], ncb0[2];
    #pragma unroll
    for (int k = 0; k < 2; ++k) {
        const float wf = (float)(2 * lane + k);
        const float v0 = fminf(fmaxf(wf + ym, 0.f), 128.f);
        const float v1 = fminf(fmaxf(wf + yM + 1.f, 0.f), 128.f);
        const float j0f = fminf(floorf(v0), 127.f);
        const float j1f = fminf(floorf(v1), 127.f);
        j0[k] = (int)j0f;  j1[k] = (int)j1f;
        const float b0 = v0 - j0f, b1 = v1 - j1f;
        b1v[k] = b1; cb1[k] = 1.f - b1;
        nb0v[k] = -b0; ncb0[k] = -(1.f - b0);
    }

    const int rsub = lane >> 5;         // 0: row h, 1: row h+1
    const int wp   = (lane & 31) * 4;   // Stage-A columns wp..wp+3
    float* Dw = Dbuf[wid];
    float* Dt = Dtail[wid];

    // row-interp coefficients + row addresses for row (h + rsub)
    auto rowCoef = [&](int h, const float*& p0, const float*& p1,
                       float& a0, float& a1, float& ca0, float& ca1) {
        const float hf = (float)(h + rsub);
        const float u0 = fminf(fmaxf(hf + xm, 0.f), 128.f);
        const float u1 = fminf(fmaxf(hf + xM + 1.f, 0.f), 128.f);
        const float i0f = fminf(floorf(u0), 127.f);
        const float i1f = fminf(floorf(u1), 127.f);
        a0 = u0 - i0f; a1 = u1 - i1f; ca0 = 1.f - a0; ca1 = 1.f - a1;
        p0 = I + (int)i0f * STRIDE;
        p1 = I + (int)i1f * STRIDE;
    };

    // ---- precompute col-128 Drow tails: lane r handles row hbase+r ----
    {
        const float hf = (float)(hbase + lane);
        const float u0 = fminf(fmaxf(hf + xm, 0.f), 128.f);
        const float u1 = fminf(fmaxf(hf + xM + 1.f, 0.f), 128.f);
        const float i0f = fminf(floorf(u0), 127.f);
        const float i1f = fminf(floorf(u1), 127.f);
        const int i0 = (int)i0f, i1 = (int)i1f;
        const float a0 = u0 - i0f, a1 = u1 - i1f;
        const float t = (1.f - a1) * I[i1 * STRIDE + 128] + a1 * I[(i1 + 1) * STRIDE + 128]
                      - (1.f - a0) * I[i0 * STRIDE + 128] - a0 * I[(i0 + 1) * STRIDE + 128];
        Dt[(lane & 1) * 32 + (lane >> 1)] = t;   // index [rsub*32 + it]
    }
    // same-wave DS ops are serviced in order -> no barrier needed (wave-private)

    float* outf = out + ((size_t)bc * F + f) * (size_t)(H * W);

    // ---- software-pipelined main loop ----
    const float *p0, *p1;
    float a0, a1, ca0, ca1;
    rowCoef(hbase, p0, p1, a0, a1, ca0, ca1);
    float4 q0  = *(const float4*)(p0 + wp);
    float4 q0b = *(const float4*)(p0 + STRIDE + wp);
    float4 q1  = *(const float4*)(p1 + wp);
    float4 q1b = *(const float4*)(p1 + STRIDE + wp);

    for (int it = 0; it < 32; ++it) {
        const int h = hbase + it * 2;

        // Stage A: row-interpolated difference -> Dw
        float4 d;
        d.x = ca1 * q1.x + a1 * q1b.x - ca0 * q0.x - a0 * q0b.x;
        d.y = ca1 * q1.y + a1 * q1b.y - ca0 * q0.y - a0 * q0b.y;
        d.z = ca1 * q1.z + a1 * q1b.z - ca0 * q0.z - a0 * q0b.z;
        d.w = ca1 * q1.w + a1 * q1b.w - ca0 * q0.w - a0 * q0b.w;
        *(float4*)(Dw + rsub * STRIDE + wp) = d;
        if ((lane & 31) == 31) Dw[rsub * STRIDE + 128] = Dt[rsub * 32 + it];

        // Stage B gathers: issue loads (in-order DS -> sees the writes above)
        float Dj0[2][2], Dj0p[2][2], Dj1[2][2], Dj1p[2][2];
        #pragma unroll
        for (int rr = 0; rr < 2; ++rr) {
            const float* Dr = Dw + rr * STRIDE;
            #pragma unroll
            for (int k = 0; k < 2; ++k) {
                const float* pj0 = Dr + j0[k];
                const float* pj1 = Dr + j1[k];
                Dj0[rr][k] = pj0[0]; Dj0p[rr][k] = pj0[1];
                Dj1[rr][k] = pj1[0]; Dj1p[rr][k] = pj1[1];
            }
        }

        // prefetch next iteration's Stage-A rows (independent of Dw)
        rowCoef(h + 2, p0, p1, a0, a1, ca0, ca1);
        q0  = *(const float4*)(p0 + wp);
        q0b = *(const float4*)(p0 + STRIDE + wp);
        q1  = *(const float4*)(p1 + wp);
        q1b = *(const float4*)(p1 + STRIDE + wp);

        // Stage B compute + ONE float2 store per row (cols 2*lane, 2*lane+1)
        #pragma unroll
        for (int rr = 0; rr < 2; ++rr) {
            float2 o;
            o.x = cb1[0] * Dj1[rr][0] + b1v[0] * Dj1p[rr][0]
                + ncb0[0] * Dj0[rr][0] + nb0v[0] * Dj0p[rr][0];
            o.y = cb1[1] * Dj1[rr][1] + b1v[1] * Dj1p[rr][1]
                + ncb0[1] * Dj0[rr][1] + nb0v[1] * Dj0p[rr][1];
            *(float2*)(outf + (size_t)(h + rr) * W + 2 * lane) = o;
        }
    }
}

extern "C" void kernel_launch(void* const* d_in, const int* in_sizes, int n_in,
                              void* d_out, int out_size, void* d_ws, size_t ws_size,
                              hipStream_t stream) {
    const float* in    = (const float*)d_in[0];
    const float* x_min = (const float*)d_in[1];
    const float* x_max = (const float*)d_in[2];
    const float* y_min = (const float*)d_in[3];
    const float* y_max = (const float*)d_in[4];
    float* outp = (float*)d_out;

    boxconv_kernel<<<dim3(8 * 32 * 2), dim3(512), 0, stream>>>(
        in, x_min, x_max, y_min, y_max, outp);
}